// Round 1
// baseline (546.816 us; speedup 1.0000x reference)
//
#include <hip/hip_runtime.h>
#include <cstdint>
#include <cstddef>

#define MDIM 8192
#define NDIM 4096
#define KDIM 4096

typedef __attribute__((ext_vector_type(8))) __bf16 bf16x8;
typedef __attribute__((ext_vector_type(4))) float floatx4;

typedef __attribute__((address_space(3))) void lds_t;
typedef __attribute__((address_space(1))) void glb_t;

__device__ __forceinline__ unsigned short f32_to_bf16(float f) {
  unsigned int u = __float_as_uint(f);
  u += 0x7FFFu + ((u >> 16) & 1u);   // RNE
  return (unsigned short)(u >> 16);
}

// e2m1 magnitude for code c in 0..7: {0,0.5,1,1.5,2,3,4,6}
__device__ __forceinline__ float fp4_mag(int c) {
  int e = (c >> 1) & 3, m = c & 1;
  int sh = e ? (e - 1) : 0;
  return e ? 0.5f * (float)((2 + m) << sh) : 0.5f * (float)m;
}

// ---------------- prepass 1: x fp32 -> bf16 ----------------
__global__ __launch_bounds__(256) void conv_x_kernel(const float* __restrict__ x,
                                                     unsigned short* __restrict__ xb) {
  const int t = blockIdx.x * 256 + threadIdx.x;     // 0 .. 4194303, 8 elems each
  const float4* src = (const float4*)x + (size_t)t * 2;
  float4 a = src[0], b = src[1];
  union { unsigned short us[8]; uint4 u4; } o;
  o.us[0] = f32_to_bf16(a.x); o.us[1] = f32_to_bf16(a.y);
  o.us[2] = f32_to_bf16(a.z); o.us[3] = f32_to_bf16(a.w);
  o.us[4] = f32_to_bf16(b.x); o.us[5] = f32_to_bf16(b.y);
  o.us[6] = f32_to_bf16(b.z); o.us[7] = f32_to_bf16(b.w);
  ((uint4*)xb)[t] = o.u4;
}

// ---------------- prepass 2: dequant weights -> bf16 [N][K] ----------------
// thread t handles one 16-element scale block = 8 packed bytes (stored 1/int32)
__global__ __launch_bounds__(256) void dequant_kernel(const int* __restrict__ packed,
                                                      const float* __restrict__ scales,
                                                      unsigned short* __restrict__ wb) {
  const int t = blockIdx.x * 256 + threadIdx.x;     // 0 .. 1048575
  const int4* p = (const int4*)packed + (size_t)t * 2;
  int4 pa = p[0], pb = p[1];
  float s = scales[t];
  int bytes[8] = {pa.x, pa.y, pa.z, pa.w, pb.x, pb.y, pb.z, pb.w};
  union { unsigned short us[16]; uint4 u4[2]; } o;
#pragma unroll
  for (int i = 0; i < 8; ++i) {
    int by = bytes[i] & 255;
    int hi = by >> 4, lo = by & 15;                 // even idx = high nibble
    float vh = fp4_mag(hi & 7) * s; if (hi & 8) vh = -vh;
    float vl = fp4_mag(lo & 7) * s; if (lo & 8) vl = -vl;
    o.us[2 * i]     = f32_to_bf16(vh);
    o.us[2 * i + 1] = f32_to_bf16(vl);
  }
  uint4* dst = (uint4*)(wb + (size_t)t * 16);
  dst[0] = o.u4[0]; dst[1] = o.u4[1];
}

// ---------------- main GEMM: C[M,N] = A[M,K] * B[N,K]^T + bias ----------------
// m97 structure: 128x128 block tile, BK=32, 4 waves x (4x4) 16x16x32 bf16 MFMA,
// global_load_lds width-16 staging (LDS dest = wave-uniform base + lane*16,
// so tiles are row-major 128x32 UNPADDED).
__global__ __launch_bounds__(256, 3) void gemm_kernel(const __bf16* __restrict__ A,
                                                      const __bf16* __restrict__ B,
                                                      const float* __restrict__ bias,
                                                      float* __restrict__ C) {
  __shared__ __bf16 As[128 * 32];
  __shared__ __bf16 Bs[128 * 32];
  const int t = threadIdx.x;
  const int wave = t >> 6, lane = t & 63;
  const int quad = lane >> 4, r16 = lane & 15;
  const int wm = (wave >> 1) * 64, wn = (wave & 1) * 64;
  const int m0 = blockIdx.y * 128, n0 = blockIdx.x * 128;

  floatx4 acc[4][4] = {};

  // staging map: flat id f covers tile row f>>2, cols (f&3)*8 ; LDS byte f*16
  const int sr = t >> 2;            // 0..63
  const int sc = (t & 3) * 8;       // 0,8,16,24

  const __bf16* ga = A + (size_t)(m0 + sr) * KDIM + sc;
  const __bf16* gb = B + (size_t)(n0 + sr) * KDIM + sc;

  for (int k0 = 0; k0 < KDIM; k0 += 32) {
    __builtin_amdgcn_global_load_lds((const glb_t*)(ga),
                                     (lds_t*)(As + wave * 512), 16, 0, 0);
    __builtin_amdgcn_global_load_lds((const glb_t*)(ga + (size_t)64 * KDIM),
                                     (lds_t*)(As + 2048 + wave * 512), 16, 0, 0);
    __builtin_amdgcn_global_load_lds((const glb_t*)(gb),
                                     (lds_t*)(Bs + wave * 512), 16, 0, 0);
    __builtin_amdgcn_global_load_lds((const glb_t*)(gb + (size_t)64 * KDIM),
                                     (lds_t*)(Bs + 2048 + wave * 512), 16, 0, 0);
    ga += 32; gb += 32;
    __syncthreads();

    bf16x8 af[4], bfr[4];
#pragma unroll
    for (int i = 0; i < 4; ++i) {
      // A-operand: lane holds A[m = lane&15][k = quad*8 + j]
      af[i]  = *(const bf16x8*)(As + (wm + i * 16 + r16) * 32 + quad * 8);
      // B-operand mirrors A: lane holds B[k = quad*8+j][n = lane&15] = w[n][k]
      bfr[i] = *(const bf16x8*)(Bs + (wn + i * 16 + r16) * 32 + quad * 8);
    }
#pragma unroll
    for (int i = 0; i < 4; ++i)
#pragma unroll
      for (int j = 0; j < 4; ++j)
        acc[i][j] = __builtin_amdgcn_mfma_f32_16x16x32_bf16(af[i], bfr[j], acc[i][j], 0, 0, 0);
    __syncthreads();
  }

  // epilogue: C/D layout col = lane&15, row = quad*4 + reg
  float bv[4];
#pragma unroll
  for (int j = 0; j < 4; ++j) bv[j] = bias[n0 + wn + j * 16 + r16];
#pragma unroll
  for (int i = 0; i < 4; ++i) {
    const int gm = m0 + wm + i * 16 + quad * 4;
#pragma unroll
    for (int j = 0; j < 4; ++j) {
      float* cp = C + (size_t)gm * NDIM + (n0 + wn + j * 16 + r16);
#pragma unroll
      for (int r = 0; r < 4; ++r)
        cp[(size_t)r * NDIM] = acc[i][j][r] + bv[j];
    }
  }
}

// ---------------- fallback (ws too small): fused naive ----------------
__global__ __launch_bounds__(256) void fused_fallback(const float* __restrict__ x,
                                                      const int* __restrict__ packed,
                                                      const float* __restrict__ scales,
                                                      const float* __restrict__ bias,
                                                      float* __restrict__ out) {
  const int n = blockIdx.x * 256 + threadIdx.x;
  const int m = blockIdx.y;
  const float* xr = x + (size_t)m * KDIM;
  const int* pr = packed + (size_t)n * (KDIM / 2);
  const float* sc = scales + (size_t)n * (KDIM / 16);
  float acc = 0.f;
  for (int kb = 0; kb < KDIM / 16; ++kb) {
    float s = sc[kb];
    float part = 0.f;
#pragma unroll
    for (int i = 0; i < 8; ++i) {
      int by = pr[kb * 8 + i] & 255;
      int hi = by >> 4, lo = by & 15;
      float vh = fp4_mag(hi & 7); if (hi & 8) vh = -vh;
      float vl = fp4_mag(lo & 7); if (lo & 8) vl = -vl;
      part += xr[kb * 16 + 2 * i] * vh + xr[kb * 16 + 2 * i + 1] * vl;
    }
    acc += s * part;
  }
  out[(size_t)m * NDIM + n] = acc + bias[n];
}

extern "C" void kernel_launch(void* const* d_in, const int* in_sizes, int n_in,
                              void* d_out, int out_size, void* d_ws, size_t ws_size,
                              hipStream_t stream) {
  const float* x      = (const float*)d_in[0];
  const int*   packed = (const int*)d_in[1];
  const float* scales = (const float*)d_in[2];
  const float* bias   = (const float*)d_in[3];
  float* out = (float*)d_out;

  const size_t needA = (size_t)MDIM * KDIM * 2;   // 64 MB bf16 x
  const size_t needW = (size_t)NDIM * KDIM * 2;   // 32 MB bf16 w

  if (ws_size >= needA + needW) {
    unsigned short* xb = (unsigned short*)d_ws;
    unsigned short* wb = (unsigned short*)((char*)d_ws + needA);
    conv_x_kernel<<<(MDIM * KDIM / 8) / 256, 256, 0, stream>>>(x, xb);
    dequant_kernel<<<(NDIM * KDIM / 16) / 256, 256, 0, stream>>>(packed, scales, wb);
    dim3 grid(NDIM / 128, MDIM / 128);
    gemm_kernel<<<grid, 256, 0, stream>>>((const __bf16*)xb, (const __bf16*)wb, bias, out);
  } else {
    dim3 grid(NDIM / 256, MDIM);
    fused_fallback<<<grid, 256, 0, stream>>>(x, packed, scales, bias, out);
  }
}